// Round 5
// baseline (266.883 us; speedup 1.0000x reference)
//
#include <hip/hip_runtime.h>
#include <stdint.h>

#define NF 512
#define OUT_F 16
#define PAD_DEG 128
#define GBM 64
#define GBN 128
#define GBK 32
#define NCHUNK 8   // 512/64 feature chunks in agg

typedef __attribute__((ext_vector_type(8))) short short8v;
typedef __attribute__((ext_vector_type(4))) float f32x4;

// async 16B/lane global->LDS: lds dst is wave-uniform base + lane*16
#define GLOAD_LDS16(g, l) \
  __builtin_amdgcn_global_load_lds((const __attribute__((address_space(1))) unsigned int*)(g), \
                                   (__attribute__((address_space(3))) unsigned int*)(l), 16, 0, 0)

// ---------- helpers ----------

__device__ __forceinline__ void split2(float x, short& h, short& l) {
    unsigned u = __builtin_bit_cast(unsigned, x);
    unsigned hb = (u + 0x7fffu + ((u >> 16) & 1u)) & 0xffff0000u;  // RNE to bf16
    h = (short)(hb >> 16);
    float r = x - __builtin_bit_cast(float, hb);
    unsigned v = __builtin_bit_cast(unsigned, r);
    unsigned lb = (v + 0x7fffu + ((v >> 16) & 1u)) & 0xffff0000u;
    l = (short)(lb >> 16);
}

// ---------- edge prep: in-degree count + padded adjacency fill in ONE pass ----------

__global__ void edge_prep_kernel(const int* __restrict__ src, const int* __restrict__ dst,
                                 int* __restrict__ counts, int* __restrict__ src_pad, int E) {
    int e = blockIdx.x * blockDim.x + threadIdx.x;
    if (e < E) {
        int d = dst[e];
        int slot = atomicAdd(&counts[d], 1);
        if (slot < PAD_DEG) src_pad[(size_t)d * PAD_DEG + slot] = src[e];
    }
}

// ---------- weight split+transpose: W[k][n] fp32 -> WhiT/WloT[n][k] bf16 (both W1,W2) ----------

__global__ __launch_bounds__(256) void convert_w_kernel(
    const float* __restrict__ W1, const float* __restrict__ W2,
    short* __restrict__ hi1, short* __restrict__ lo1,
    short* __restrict__ hi2, short* __restrict__ lo2) {
    __shared__ float tile[64][65];
    int id = blockIdx.x;
    const float* W;  short *WH, *WL;
    if (id < 64) { W = W1; WH = hi1; WL = lo1; }
    else         { W = W2; WH = hi2; WL = lo2; id -= 64; }
    int k0 = (id & 7) * 64, n0 = (id >> 3) * 64;
    int tr = threadIdx.x >> 4;
    int tc4 = (threadIdx.x & 15) * 4;
#pragma unroll
    for (int i = 0; i < 4; ++i) {
        int r = tr + i * 16;
        float4 v = *(const float4*)(W + (size_t)(k0 + r) * NF + n0 + tc4);
        tile[r][tc4 + 0] = v.x; tile[r][tc4 + 1] = v.y;
        tile[r][tc4 + 2] = v.z; tile[r][tc4 + 3] = v.w;
    }
    __syncthreads();
#pragma unroll
    for (int i = 0; i < 4; ++i) {
        int n = tr + i * 16;
        short h[4], l[4];
#pragma unroll
        for (int j = 0; j < 4; ++j) split2(tile[tc4 + j][n], h[j], l[j]);
        size_t off = (size_t)(n0 + n) * NF + k0 + tc4;
        *(short4*)(WH + off) = make_short4(h[0], h[1], h[2], h[3]);
        *(short4*)(WL + off) = make_short4(l[0], l[1], l[2], l[3]);
    }
}

// ---------- x fp32 -> split bf16 hi/lo [Mp][512], zero pad rows ----------

__global__ __launch_bounds__(256) void convert_x_kernel(
    const float* __restrict__ x, short* __restrict__ xhi, short* __restrict__ xlo,
    int Nreal, int Mp) {
    int idx = blockIdx.x * 256 + threadIdx.x;
    int row = idx >> 7;
    int c4 = (idx & 127) * 4;
    if (row >= Mp) return;
    float4 v = make_float4(0.f, 0.f, 0.f, 0.f);
    if (row < Nreal) v = *(const float4*)(x + (size_t)row * NF + c4);
    short h[4], l[4];
    split2(v.x, h[0], l[0]); split2(v.y, h[1], l[1]);
    split2(v.z, h[2], l[2]); split2(v.w, h[3], l[3]);
    size_t off = (size_t)row * NF + c4;
    *(short4*)(xhi + off) = make_short4(h[0], h[1], h[2], h[3]);
    *(short4*)(xlo + off) = make_short4(l[0], l[1], l[2], l[3]);
}

// ---------- split-bf16 MFMA GEMM: C[m,:] = rsqrt(deg[m]) * (A[m,:] @ B) ----------
// 64x128 tile, 4 waves (wave tile 32x64) -> 632 blocks (load balance over 256 CUs).

__global__ __launch_bounds__(256) void gemm_mfma_kernel(
    const short* __restrict__ Ahi, const short* __restrict__ Alo,
    const short* __restrict__ BhiT, const short* __restrict__ BloT,
    const int* __restrict__ counts, float* __restrict__ C) {
    __shared__ short lds[2 * GBM * GBK + 2 * GBN * GBK];  // 24 KB
    short* As_hi = lds;                                   // [64][32]
    short* As_lo = lds + GBM * GBK;
    short* Bs_hi = lds + 2 * GBM * GBK;                   // [128][32]
    short* Bs_lo = lds + 2 * GBM * GBK + GBN * GBK;

    int t = threadIdx.x;
    int w = t >> 6, lane = t & 63, l15 = lane & 15, q = lane >> 4;
    int m0 = (blockIdx.x >> 2) * GBM;   // adjacent blocks share the A stripe
    int n0 = (blockIdx.x & 3) * GBN;
    int wr = w >> 1, wc = w & 1;        // 2x2 wave grid; wave tile 32x64

    // per-lane staging source: lane -> (row lane/4, k-chunk (lane%4)*8 shorts)
    int gr = lane >> 2;
    int gk = (lane & 3) * 8;
    const short* Ahi_g = Ahi + (size_t)(m0 + w * 16 + gr) * NF + gk;
    const short* Alo_g = Alo + (size_t)(m0 + w * 16 + gr) * NF + gk;
    const short* Bhi_g0 = BhiT + (size_t)(n0 + w * 16 + gr) * NF + gk;
    const short* Bhi_g1 = BhiT + (size_t)(n0 + (w + 4) * 16 + gr) * NF + gk;
    const short* Blo_g0 = BloT + (size_t)(n0 + w * 16 + gr) * NF + gk;
    const short* Blo_g1 = BloT + (size_t)(n0 + (w + 4) * 16 + gr) * NF + gk;
    // wave-uniform LDS destinations
    short* As_hi_d = As_hi + w * 16 * GBK;
    short* As_lo_d = As_lo + w * 16 * GBK;
    short* Bs_hi_d0 = Bs_hi + w * 16 * GBK;
    short* Bs_hi_d1 = Bs_hi + (w + 4) * 16 * GBK;
    short* Bs_lo_d0 = Bs_lo + w * 16 * GBK;
    short* Bs_lo_d1 = Bs_lo + (w + 4) * 16 * GBK;

    f32x4 acc[2][4] = {};

    for (int k0 = 0; k0 < NF; k0 += GBK) {
        GLOAD_LDS16(Ahi_g + k0, As_hi_d);
        GLOAD_LDS16(Alo_g + k0, As_lo_d);
        GLOAD_LDS16(Bhi_g0 + k0, Bs_hi_d0);
        GLOAD_LDS16(Bhi_g1 + k0, Bs_hi_d1);
        GLOAD_LDS16(Blo_g0 + k0, Bs_lo_d0);
        GLOAD_LDS16(Blo_g1 + k0, Bs_lo_d1);
        __syncthreads();

        short8v ahi[2], alo[2], bhi[4], blo[4];
#pragma unroll
        for (int r = 0; r < 2; ++r) {
            int off = (wr * 32 + r * 16 + l15) * GBK + q * 8;
            ahi[r] = *(const short8v*)(As_hi + off);
            alo[r] = *(const short8v*)(As_lo + off);
        }
#pragma unroll
        for (int c = 0; c < 4; ++c) {
            int off = (wc * 64 + c * 16 + l15) * GBK + q * 8;
            bhi[c] = *(const short8v*)(Bs_hi + off);
            blo[c] = *(const short8v*)(Bs_lo + off);
        }
#pragma unroll
        for (int r = 0; r < 2; ++r)
#pragma unroll
            for (int c = 0; c < 4; ++c) {
                acc[r][c] = __builtin_amdgcn_mfma_f32_16x16x32_bf16(ahi[r], bhi[c], acc[r][c], 0, 0, 0);
                acc[r][c] = __builtin_amdgcn_mfma_f32_16x16x32_bf16(ahi[r], blo[c], acc[r][c], 0, 0, 0);
                acc[r][c] = __builtin_amdgcn_mfma_f32_16x16x32_bf16(alo[r], bhi[c], acc[r][c], 0, 0, 0);
            }
        __syncthreads();
    }

    // C/D layout: col = l15, row = q*4 + reg
#pragma unroll
    for (int r = 0; r < 2; ++r)
#pragma unroll
        for (int i = 0; i < 4; ++i) {
            int row = m0 + wr * 32 + r * 16 + q * 4 + i;
            float dv = rsqrtf((float)counts[row] + 1.0f);
#pragma unroll
            for (int c = 0; c < 4; ++c) {
                int col = n0 + wc * 64 + c * 16 + l15;
                C[(size_t)row * NF + col] = acc[r][c][i] * dv;
            }
        }
}

// ---------- quarter-wave CSR aggregation, optionally with fused head GEMV ----------
// chunk = blockIdx.x & 7 rides block->XCD round-robin (gather stays per-XCD-L2-resident).
// lane = 16*g + j: quarter g handles edge e+4t+g, lane loads float4; butterfly-reduce quarters.
// fuse_head=0: emit split bf16 hi/lo (next GEMM's A).
// fuse_head=1: compute 16 partial head dots for this chunk, atomicAdd into head_out.

__global__ __launch_bounds__(256) void agg_kernel(
    const float* __restrict__ hs, const int* __restrict__ counts,
    const int* __restrict__ src_pad, const float* __restrict__ bias,
    short* __restrict__ out_hi, short* __restrict__ out_lo,
    const float* __restrict__ Wl, const float* __restrict__ bl,
    float* __restrict__ head_out, int Mreal, int fuse_head) {
    __shared__ __align__(16) float WlT[OUT_F][68];  // [o][feat-in-chunk], padded rows
    int chunk = blockIdx.x & (NCHUNK - 1);
    if (fuse_head) {
        for (int i = threadIdx.x; i < 64 * OUT_F; i += 256) {
            int fr = i >> 4, o = i & 15;
            WlT[o][fr] = Wl[(size_t)(chunk * 64 + fr) * OUT_F + o];
        }
        __syncthreads();
    }

    int node = (blockIdx.x >> 3) * 4 + (threadIdx.x >> 6);
    int lane = threadIdx.x & 63;
    int g = lane >> 4;
    int j = lane & 15;
    int f4 = chunk * 64 + j * 4;
    size_t obase = (size_t)node * NF + f4;

    if (node >= Mreal) {  // pad rows must be zero when consumed as GEMM-A
        if (!fuse_head && g == 0) {
            *(short4*)(out_hi + obase) = make_short4(0, 0, 0, 0);
            *(short4*)(out_lo + obase) = make_short4(0, 0, 0, 0);
        }
        return;
    }

    int cnt = counts[node];
    cnt = cnt < PAD_DEG ? cnt : PAD_DEG;
    const int* sp = src_pad + (size_t)node * PAD_DEG;

    float4 acc = make_float4(0.f, 0.f, 0.f, 0.f);
    for (int e = 0; e < cnt; e += 16) {
        int   s[4];
        float msk[4];
#pragma unroll
        for (int tq = 0; tq < 4; ++tq) {
            int idx = e + tq * 4 + g;
            int ok = idx < cnt;
            s[tq] = ok ? sp[idx] : node;   // safe fallback row (hot)
            msk[tq] = ok ? 1.f : 0.f;
        }
#pragma unroll
        for (int tq = 0; tq < 4; ++tq) {
            float4 v = *(const float4*)(hs + (size_t)s[tq] * NF + f4);
            acc.x = fmaf(msk[tq], v.x, acc.x);
            acc.y = fmaf(msk[tq], v.y, acc.y);
            acc.z = fmaf(msk[tq], v.z, acc.z);
            acc.w = fmaf(msk[tq], v.w, acc.w);
        }
    }

    // reduce across the 4 quarter-waves
    acc.x += __shfl_xor(acc.x, 16); acc.y += __shfl_xor(acc.y, 16);
    acc.z += __shfl_xor(acc.z, 16); acc.w += __shfl_xor(acc.w, 16);
    acc.x += __shfl_xor(acc.x, 32); acc.y += __shfl_xor(acc.y, 32);
    acc.z += __shfl_xor(acc.z, 32); acc.w += __shfl_xor(acc.w, 32);

    if (g != 0) return;

    float4 self = *(const float4*)(hs + obase);
    float4 bv = *(const float4*)(bias + f4);
    float dv = rsqrtf((float)counts[node] + 1.0f);
    float4 o;
    o.x = fmaxf(dv * (acc.x + self.x) + bv.x, 0.f);
    o.y = fmaxf(dv * (acc.y + self.y) + bv.y, 0.f);
    o.z = fmaxf(dv * (acc.z + self.z) + bv.z, 0.f);
    o.w = fmaxf(dv * (acc.w + self.w) + bv.w, 0.f);

    if (!fuse_head) {
        short h[4], l[4];
        split2(o.x, h[0], l[0]); split2(o.y, h[1], l[1]);
        split2(o.z, h[2], l[2]); split2(o.w, h[3], l[3]);
        *(short4*)(out_hi + obase) = make_short4(h[0], h[1], h[2], h[3]);
        *(short4*)(out_lo + obase) = make_short4(l[0], l[1], l[2], l[3]);
    } else {
        // lane j computes head output o=j partial over this 64-feat chunk;
        // h2 quads live 4-per-lane across lanes 0..15 -> shfl broadcast.
        float p = 0.f;
#pragma unroll
        for (int r = 0; r < 16; ++r) {
            float4 wv = *(const float4*)&WlT[j][r * 4];
            p = fmaf(__shfl(o.x, r, 16), wv.x, p);
            p = fmaf(__shfl(o.y, r, 16), wv.y, p);
            p = fmaf(__shfl(o.z, r, 16), wv.z, p);
            p = fmaf(__shfl(o.w, r, 16), wv.w, p);
        }
        if (chunk == 0) p += bl[j];
        atomicAdd(head_out + (size_t)node * OUT_F + j, p);
    }
}

// ---------- launch ----------

extern "C" void kernel_launch(void* const* d_in, const int* in_sizes, int n_in,
                              void* d_out, int out_size, void* d_ws, size_t ws_size,
                              hipStream_t stream) {
    const float* x  = (const float*)d_in[0];
    const int* eidx = (const int*)d_in[1];
    const float* W1 = (const float*)d_in[2];
    const float* b1 = (const float*)d_in[3];
    const float* W2 = (const float*)d_in[4];
    const float* b2 = (const float*)d_in[5];
    const float* Wl = (const float*)d_in[6];
    const float* bl = (const float*)d_in[7];

    int N = in_sizes[0] / NF;
    int E = in_sizes[1] / 2;
    int Mp = (N + GBM - 1) & ~(GBM - 1);
    const int* src = eidx;
    const int* dst = eidx + E;

    char* p = (char*)d_ws;
    auto carve = [&](size_t bytes) -> void* {
        void* r = (void*)p;
        p += (bytes + 255) & ~(size_t)255;
        return r;
    };
    float* hbuf     = (float*)carve((size_t)Mp * NF * sizeof(float));  // GEMM outputs
    short* splitbuf = (short*)carve((size_t)Mp * NF * 2 * sizeof(short));
    short* s_hi     = splitbuf;                       // x-split, then agg1-split (gemm2 A)
    short* s_lo     = splitbuf + (size_t)Mp * NF;
    short* W1hiT    = (short*)carve((size_t)NF * NF * sizeof(short));
    short* W1loT    = (short*)carve((size_t)NF * NF * sizeof(short));
    short* W2hiT    = (short*)carve((size_t)NF * NF * sizeof(short));
    short* W2loT    = (short*)carve((size_t)NF * NF * sizeof(short));
    int*   counts   = (int*)carve((size_t)Mp * sizeof(int));
    int*   src_pad  = (int*)carve((size_t)N * PAD_DEG * sizeof(int));

    hipMemsetAsync(counts, 0, (size_t)Mp * sizeof(int), stream);
    hipMemsetAsync(d_out, 0, (size_t)out_size * sizeof(float), stream);  // fused head accumulates

    edge_prep_kernel<<<dim3((E + 255) / 256), dim3(256), 0, stream>>>(src, dst, counts, src_pad, E);
    convert_w_kernel<<<dim3(128), dim3(256), 0, stream>>>(W1, W2, W1hiT, W1loT, W2hiT, W2loT);
    convert_x_kernel<<<dim3(Mp * (NF / 4) / 256), dim3(256), 0, stream>>>(x, s_hi, s_lo, N, Mp);

    dim3 gg((Mp / GBM) * (NF / GBN));   // 632 blocks
    dim3 ga((Mp / 4) * NCHUNK);

    // layer 1
    gemm_mfma_kernel<<<gg, dim3(256), 0, stream>>>(s_hi, s_lo, W1hiT, W1loT, counts, hbuf);
    agg_kernel<<<ga, dim3(256), 0, stream>>>(hbuf, counts, src_pad, b1,
                                             s_hi, s_lo, (const float*)nullptr,
                                             (const float*)nullptr, (float*)nullptr, N, 0);
    // layer 2 + fused head
    gemm_mfma_kernel<<<gg, dim3(256), 0, stream>>>(s_hi, s_lo, W2hiT, W2loT, counts, hbuf);
    agg_kernel<<<ga, dim3(256), 0, stream>>>(hbuf, counts, src_pad, b2,
                                             (short*)nullptr, (short*)nullptr, Wl, bl,
                                             (float*)d_out, N, 1);
}

// Round 6
// 205.401 us; speedup vs baseline: 1.2993x; 1.2993x over previous
//
#include <hip/hip_runtime.h>
#include <stdint.h>

#define NF 512
#define OUT_F 16
#define PAD_DEG 128
#define GBM 64
#define GBN 128
#define GBK 32
#define NCHUNK 4   // 512/128 feature chunks in agg

typedef __attribute__((ext_vector_type(8))) short short8v;
typedef __attribute__((ext_vector_type(4))) float f32x4;

// async 16B/lane global->LDS: lds dst is wave-uniform base + lane*16
#define GLOAD_LDS16(g, l) \
  __builtin_amdgcn_global_load_lds((const __attribute__((address_space(1))) unsigned int*)(g), \
                                   (__attribute__((address_space(3))) unsigned int*)(l), 16, 0, 0)

// ---------- helpers ----------

__device__ __forceinline__ void split2(float x, short& h, short& l) {
    unsigned u = __builtin_bit_cast(unsigned, x);
    unsigned hb = (u + 0x7fffu + ((u >> 16) & 1u)) & 0xffff0000u;  // RNE to bf16
    h = (short)(hb >> 16);
    float r = x - __builtin_bit_cast(float, hb);
    unsigned v = __builtin_bit_cast(unsigned, r);
    unsigned lb = (v + 0x7fffu + ((v >> 16) & 1u)) & 0xffff0000u;
    l = (short)(lb >> 16);
}

__device__ __forceinline__ unsigned short bf16r(float x) {
    unsigned u = __builtin_bit_cast(unsigned, x);
    return (unsigned short)((u + 0x7fffu + ((u >> 16) & 1u)) >> 16);
}

// ---------- edge prep: in-degree count + padded adjacency fill in ONE pass ----------

__global__ void edge_prep_kernel(const int* __restrict__ src, const int* __restrict__ dst,
                                 int* __restrict__ counts, int* __restrict__ src_pad, int E) {
    int e = blockIdx.x * blockDim.x + threadIdx.x;
    if (e < E) {
        int d = dst[e];
        int slot = atomicAdd(&counts[d], 1);
        if (slot < PAD_DEG) src_pad[(size_t)d * PAD_DEG + slot] = src[e];
    }
}

// ---------- weight split+transpose: W[k][n] fp32 -> WhiT/WloT[n][k] bf16 (both W1,W2) ----------

__global__ __launch_bounds__(256) void convert_w_kernel(
    const float* __restrict__ W1, const float* __restrict__ W2,
    short* __restrict__ hi1, short* __restrict__ lo1,
    short* __restrict__ hi2, short* __restrict__ lo2) {
    __shared__ float tile[64][65];
    int id = blockIdx.x;
    const float* W;  short *WH, *WL;
    if (id < 64) { W = W1; WH = hi1; WL = lo1; }
    else         { W = W2; WH = hi2; WL = lo2; id -= 64; }
    int k0 = (id & 7) * 64, n0 = (id >> 3) * 64;
    int tr = threadIdx.x >> 4;
    int tc4 = (threadIdx.x & 15) * 4;
#pragma unroll
    for (int i = 0; i < 4; ++i) {
        int r = tr + i * 16;
        float4 v = *(const float4*)(W + (size_t)(k0 + r) * NF + n0 + tc4);
        tile[r][tc4 + 0] = v.x; tile[r][tc4 + 1] = v.y;
        tile[r][tc4 + 2] = v.z; tile[r][tc4 + 3] = v.w;
    }
    __syncthreads();
#pragma unroll
    for (int i = 0; i < 4; ++i) {
        int n = tr + i * 16;
        short h[4], l[4];
#pragma unroll
        for (int j = 0; j < 4; ++j) split2(tile[tc4 + j][n], h[j], l[j]);
        size_t off = (size_t)(n0 + n) * NF + k0 + tc4;
        *(short4*)(WH + off) = make_short4(h[0], h[1], h[2], h[3]);
        *(short4*)(WL + off) = make_short4(l[0], l[1], l[2], l[3]);
    }
}

// ---------- x fp32 -> split bf16 hi/lo [Mp][512], zero pad rows ----------

__global__ __launch_bounds__(256) void convert_x_kernel(
    const float* __restrict__ x, short* __restrict__ xhi, short* __restrict__ xlo,
    int Nreal, int Mp) {
    int idx = blockIdx.x * 256 + threadIdx.x;
    int row = idx >> 7;
    int c4 = (idx & 127) * 4;
    if (row >= Mp) return;
    float4 v = make_float4(0.f, 0.f, 0.f, 0.f);
    if (row < Nreal) v = *(const float4*)(x + (size_t)row * NF + c4);
    short h[4], l[4];
    split2(v.x, h[0], l[0]); split2(v.y, h[1], l[1]);
    split2(v.z, h[2], l[2]); split2(v.w, h[3], l[3]);
    size_t off = (size_t)row * NF + c4;
    *(short4*)(xhi + off) = make_short4(h[0], h[1], h[2], h[3]);
    *(short4*)(xlo + off) = make_short4(l[0], l[1], l[2], l[3]);
}

// ---------- split-bf16 MFMA GEMM: Cb[m,:] = bf16(rsqrt(deg[m]) * (A[m,:] @ B)) ----------
// 64x128 tile, 4 waves (wave tile 32x64) -> 632 blocks (load balance over 256 CUs).

__global__ __launch_bounds__(256) void gemm_mfma_kernel(
    const short* __restrict__ Ahi, const short* __restrict__ Alo,
    const short* __restrict__ BhiT, const short* __restrict__ BloT,
    const int* __restrict__ counts, unsigned short* __restrict__ Cb) {
    __shared__ short lds[2 * GBM * GBK + 2 * GBN * GBK];  // 24 KB
    short* As_hi = lds;                                   // [64][32]
    short* As_lo = lds + GBM * GBK;
    short* Bs_hi = lds + 2 * GBM * GBK;                   // [128][32]
    short* Bs_lo = lds + 2 * GBM * GBK + GBN * GBK;

    int t = threadIdx.x;
    int w = t >> 6, lane = t & 63, l15 = lane & 15, q = lane >> 4;
    int m0 = (blockIdx.x >> 2) * GBM;   // adjacent blocks share the A stripe
    int n0 = (blockIdx.x & 3) * GBN;
    int wr = w >> 1, wc = w & 1;        // 2x2 wave grid; wave tile 32x64

    // per-lane staging source: lane -> (row lane/4, k-chunk (lane%4)*8 shorts)
    int gr = lane >> 2;
    int gk = (lane & 3) * 8;
    const short* Ahi_g = Ahi + (size_t)(m0 + w * 16 + gr) * NF + gk;
    const short* Alo_g = Alo + (size_t)(m0 + w * 16 + gr) * NF + gk;
    const short* Bhi_g0 = BhiT + (size_t)(n0 + w * 16 + gr) * NF + gk;
    const short* Bhi_g1 = BhiT + (size_t)(n0 + (w + 4) * 16 + gr) * NF + gk;
    const short* Blo_g0 = BloT + (size_t)(n0 + w * 16 + gr) * NF + gk;
    const short* Blo_g1 = BloT + (size_t)(n0 + (w + 4) * 16 + gr) * NF + gk;
    // wave-uniform LDS destinations
    short* As_hi_d = As_hi + w * 16 * GBK;
    short* As_lo_d = As_lo + w * 16 * GBK;
    short* Bs_hi_d0 = Bs_hi + w * 16 * GBK;
    short* Bs_hi_d1 = Bs_hi + (w + 4) * 16 * GBK;
    short* Bs_lo_d0 = Bs_lo + w * 16 * GBK;
    short* Bs_lo_d1 = Bs_lo + (w + 4) * 16 * GBK;

    f32x4 acc[2][4] = {};

    for (int k0 = 0; k0 < NF; k0 += GBK) {
        GLOAD_LDS16(Ahi_g + k0, As_hi_d);
        GLOAD_LDS16(Alo_g + k0, As_lo_d);
        GLOAD_LDS16(Bhi_g0 + k0, Bs_hi_d0);
        GLOAD_LDS16(Bhi_g1 + k0, Bs_hi_d1);
        GLOAD_LDS16(Blo_g0 + k0, Bs_lo_d0);
        GLOAD_LDS16(Blo_g1 + k0, Bs_lo_d1);
        __syncthreads();

        short8v ahi[2], alo[2], bhi[4], blo[4];
#pragma unroll
        for (int r = 0; r < 2; ++r) {
            int off = (wr * 32 + r * 16 + l15) * GBK + q * 8;
            ahi[r] = *(const short8v*)(As_hi + off);
            alo[r] = *(const short8v*)(As_lo + off);
        }
#pragma unroll
        for (int c = 0; c < 4; ++c) {
            int off = (wc * 64 + c * 16 + l15) * GBK + q * 8;
            bhi[c] = *(const short8v*)(Bs_hi + off);
            blo[c] = *(const short8v*)(Bs_lo + off);
        }
#pragma unroll
        for (int r = 0; r < 2; ++r)
#pragma unroll
            for (int c = 0; c < 4; ++c) {
                acc[r][c] = __builtin_amdgcn_mfma_f32_16x16x32_bf16(ahi[r], bhi[c], acc[r][c], 0, 0, 0);
                acc[r][c] = __builtin_amdgcn_mfma_f32_16x16x32_bf16(ahi[r], blo[c], acc[r][c], 0, 0, 0);
                acc[r][c] = __builtin_amdgcn_mfma_f32_16x16x32_bf16(alo[r], bhi[c], acc[r][c], 0, 0, 0);
            }
        __syncthreads();
    }

    // C/D layout: col = l15, row = q*4 + reg
#pragma unroll
    for (int r = 0; r < 2; ++r)
#pragma unroll
        for (int i = 0; i < 4; ++i) {
            int row = m0 + wr * 32 + r * 16 + q * 4 + i;
            float dv = rsqrtf((float)counts[row] + 1.0f);
#pragma unroll
            for (int c = 0; c < 4; ++c) {
                int col = n0 + wc * 64 + c * 16 + l15;
                Cb[(size_t)row * NF + col] = bf16r(acc[r][c][i] * dv);
            }
        }
}

// ---------- quarter-wave CSR aggregation over bf16 h-buffer ----------
// chunk = blockIdx.x & 3 (rides block->XCD round-robin; 2.5 MB slice per XCD-L2).
// lane = 16*g + j: quarter g handles 4 consecutive edges (int4 index load), lane loads
// ushort8 (16 B = 8 bf16 features at chunk*128 + j*8); butterfly-reduce quarters.
// split_out=1: emit split bf16 hi/lo (next GEMM's A). split_out=0: emit fp32 (head input).

__global__ __launch_bounds__(256) void agg_kernel(
    const unsigned short* __restrict__ hb, const int* __restrict__ counts,
    const int* __restrict__ src_pad, const float* __restrict__ bias,
    short* __restrict__ out_hi, short* __restrict__ out_lo,
    float* __restrict__ out32, int Mreal, int split_out) {
    int chunk = blockIdx.x & (NCHUNK - 1);
    int node = (blockIdx.x >> 2) * 4 + (threadIdx.x >> 6);
    int lane = threadIdx.x & 63;
    int g = lane >> 4;
    int j = lane & 15;
    int f8 = chunk * 128 + j * 8;
    size_t obase = (size_t)node * NF + f8;

    if (node >= Mreal) {  // pad rows must be zero when consumed as GEMM-A
        if (g == 0) {
            if (split_out) {
                short8v z = {0, 0, 0, 0, 0, 0, 0, 0};
                *(short8v*)(out_hi + obase) = z;
                *(short8v*)(out_lo + obase) = z;
            } else {
                *(float4*)(out32 + obase) = make_float4(0.f, 0.f, 0.f, 0.f);
                *(float4*)(out32 + obase + 4) = make_float4(0.f, 0.f, 0.f, 0.f);
            }
        }
        return;
    }

    int cntr = counts[node];
    int cnt = cntr < PAD_DEG ? cntr : PAD_DEG;
    const int* sp = src_pad + (size_t)node * PAD_DEG;

    float acc[8] = {};
    for (int e = 0; e < cnt; e += 16) {
        int4 s4 = *(const int4*)(sp + e + g * 4);   // quarter g: edges e+4g .. e+4g+3
        int base = e + g * 4;
        int sidx[4] = {s4.x, s4.y, s4.z, s4.w};
#pragma unroll
        for (int tq = 0; tq < 4; ++tq) {
            bool ok = (base + tq) < cnt;
            int srow = ok ? sidx[tq] : node;        // safe hot fallback row
            float m = ok ? 1.f : 0.f;
            uint4 pv = *(const uint4*)(hb + (size_t)srow * NF + f8);
            acc[0] = fmaf(m, __builtin_bit_cast(float, pv.x << 16), acc[0]);
            acc[1] = fmaf(m, __builtin_bit_cast(float, pv.x & 0xffff0000u), acc[1]);
            acc[2] = fmaf(m, __builtin_bit_cast(float, pv.y << 16), acc[2]);
            acc[3] = fmaf(m, __builtin_bit_cast(float, pv.y & 0xffff0000u), acc[3]);
            acc[4] = fmaf(m, __builtin_bit_cast(float, pv.z << 16), acc[4]);
            acc[5] = fmaf(m, __builtin_bit_cast(float, pv.z & 0xffff0000u), acc[5]);
            acc[6] = fmaf(m, __builtin_bit_cast(float, pv.w << 16), acc[6]);
            acc[7] = fmaf(m, __builtin_bit_cast(float, pv.w & 0xffff0000u), acc[7]);
        }
    }

#pragma unroll
    for (int k = 0; k < 8; ++k) {
        acc[k] += __shfl_xor(acc[k], 16);
        acc[k] += __shfl_xor(acc[k], 32);
    }

    if (g != 0) return;

    uint4 sv = *(const uint4*)(hb + obase);  // self row (bf16)
    float self[8];
    self[0] = __builtin_bit_cast(float, sv.x << 16);
    self[1] = __builtin_bit_cast(float, sv.x & 0xffff0000u);
    self[2] = __builtin_bit_cast(float, sv.y << 16);
    self[3] = __builtin_bit_cast(float, sv.y & 0xffff0000u);
    self[4] = __builtin_bit_cast(float, sv.z << 16);
    self[5] = __builtin_bit_cast(float, sv.z & 0xffff0000u);
    self[6] = __builtin_bit_cast(float, sv.w << 16);
    self[7] = __builtin_bit_cast(float, sv.w & 0xffff0000u);

    float dv = rsqrtf((float)cntr + 1.0f);
    float o[8];
#pragma unroll
    for (int k = 0; k < 8; ++k)
        o[k] = fmaxf(fmaf(dv, acc[k] + self[k], bias[f8 + k]), 0.f);

    if (split_out) {
        short8v h8, l8;
#pragma unroll
        for (int k = 0; k < 8; ++k) { short hh, ll; split2(o[k], hh, ll); h8[k] = hh; l8[k] = ll; }
        *(short8v*)(out_hi + obase) = h8;
        *(short8v*)(out_lo + obase) = l8;
    } else {
        *(float4*)(out32 + obase) = make_float4(o[0], o[1], o[2], o[3]);
        *(float4*)(out32 + obase + 4) = make_float4(o[4], o[5], o[6], o[7]);
    }
}

// ---------- head: out[n,o] = in[n,:] @ Wl[:,o] + bl[o] ----------

__global__ __launch_bounds__(256) void head_kernel(
    const float* __restrict__ in, const float* __restrict__ Wl,
    const float* __restrict__ bl, float* __restrict__ out, int M) {
    __shared__ float Ws[NF * OUT_F];  // 32 KB
    int tid = threadIdx.x;
    for (int i = tid; i < NF * OUT_F; i += 256) Ws[i] = Wl[i];
    __syncthreads();
    int node = blockIdx.x * 16 + (tid >> 4);
    int o = tid & 15;
    if (node >= M) return;
    const float4* row4 = (const float4*)(in + (size_t)node * NF);
    float acc = 0.f;
#pragma unroll 4
    for (int k4 = 0; k4 < NF / 4; ++k4) {
        float4 rv = row4[k4];
        int kb = k4 * 4;
        acc += rv.x * Ws[(kb + 0) * OUT_F + o] + rv.y * Ws[(kb + 1) * OUT_F + o]
             + rv.z * Ws[(kb + 2) * OUT_F + o] + rv.w * Ws[(kb + 3) * OUT_F + o];
    }
    out[(size_t)node * OUT_F + o] = acc + bl[o];
}

// ---------- launch ----------

extern "C" void kernel_launch(void* const* d_in, const int* in_sizes, int n_in,
                              void* d_out, int out_size, void* d_ws, size_t ws_size,
                              hipStream_t stream) {
    const float* x  = (const float*)d_in[0];
    const int* eidx = (const int*)d_in[1];
    const float* W1 = (const float*)d_in[2];
    const float* b1 = (const float*)d_in[3];
    const float* W2 = (const float*)d_in[4];
    const float* b2 = (const float*)d_in[5];
    const float* Wl = (const float*)d_in[6];
    const float* bl = (const float*)d_in[7];

    int N = in_sizes[0] / NF;
    int E = in_sizes[1] / 2;
    int Mp = (N + GBM - 1) & ~(GBM - 1);
    const int* src = eidx;
    const int* dst = eidx + E;

    char* p = (char*)d_ws;
    auto carve = [&](size_t bytes) -> void* {
        void* r = (void*)p;
        p += (bytes + 255) & ~(size_t)255;
        return r;
    };
    unsigned short* hbuf = (unsigned short*)carve((size_t)Mp * NF * sizeof(unsigned short));  // bf16 GEMM out
    // region reused: xhi/xlo (gemm1 A) -> agg1 split out (gemm2 A) -> agg2 fp32 out (head in)
    short* splitbuf = (short*)carve((size_t)Mp * NF * 2 * sizeof(short));
    short* s_hi     = splitbuf;
    short* s_lo     = splitbuf + (size_t)Mp * NF;
    float* aggout   = (float*)splitbuf;
    short* W1hiT    = (short*)carve((size_t)NF * NF * sizeof(short));
    short* W1loT    = (short*)carve((size_t)NF * NF * sizeof(short));
    short* W2hiT    = (short*)carve((size_t)NF * NF * sizeof(short));
    short* W2loT    = (short*)carve((size_t)NF * NF * sizeof(short));
    int*   counts   = (int*)carve((size_t)Mp * sizeof(int));
    int*   src_pad  = (int*)carve((size_t)N * PAD_DEG * sizeof(int));

    hipMemsetAsync(counts, 0, (size_t)Mp * sizeof(int), stream);

    edge_prep_kernel<<<dim3((E + 255) / 256), dim3(256), 0, stream>>>(src, dst, counts, src_pad, E);
    convert_w_kernel<<<dim3(128), dim3(256), 0, stream>>>(W1, W2, W1hiT, W1loT, W2hiT, W2loT);
    convert_x_kernel<<<dim3(Mp * (NF / 4) / 256), dim3(256), 0, stream>>>(x, s_hi, s_lo, N, Mp);

    dim3 gg((Mp / GBM) * (NF / GBN));   // 632 blocks
    dim3 ga(Mp);                        // (Mp/4 node groups) x 4 chunks

    // layer 1
    gemm_mfma_kernel<<<gg, dim3(256), 0, stream>>>(s_hi, s_lo, W1hiT, W1loT, counts, hbuf);
    agg_kernel<<<ga, dim3(256), 0, stream>>>(hbuf, counts, src_pad, b1,
                                             s_hi, s_lo, (float*)nullptr, N, 1);
    // layer 2
    gemm_mfma_kernel<<<gg, dim3(256), 0, stream>>>(s_hi, s_lo, W2hiT, W2loT, counts, hbuf);
    agg_kernel<<<ga, dim3(256), 0, stream>>>(hbuf, counts, src_pad, b2,
                                             (short*)nullptr, (short*)nullptr, aggout, N, 0);
    // head
    head_kernel<<<dim3((N + 15) / 16), dim3(256), 0, stream>>>(aggout, Wl, bl, (float*)d_out, N);
}

// Round 7
// 172.586 us; speedup vs baseline: 1.5464x; 1.1901x over previous
//
#include <hip/hip_runtime.h>
#include <stdint.h>

#define NF 512
#define OUT_F 16
#define PAD_DEG 128
#define GBM 64
#define GBN 128
#define NCHUNK 4   // 512/128 feature chunks in agg

typedef __attribute__((ext_vector_type(8))) _Float16 half8;
typedef __attribute__((ext_vector_type(4))) _Float16 half4v;
typedef __attribute__((ext_vector_type(4))) float f32x4;

// async 16B/lane global->LDS: lds dst is wave-uniform base + lane*16
#define GLOAD_LDS16(g, l) \
  __builtin_amdgcn_global_load_lds((const __attribute__((address_space(1))) unsigned int*)(g), \
                                   (__attribute__((address_space(3))) unsigned int*)(l), 16, 0, 0)

// ---------- edge prep: in-degree count + padded adjacency fill in ONE pass ----------

__global__ void edge_prep_kernel(const int* __restrict__ src, const int* __restrict__ dst,
                                 int* __restrict__ counts, int* __restrict__ src_pad, int E) {
    int e = blockIdx.x * blockDim.x + threadIdx.x;
    if (e < E) {
        int d = dst[e];
        int slot = atomicAdd(&counts[d], 1);
        if (slot < PAD_DEG) src_pad[(size_t)d * PAD_DEG + slot] = src[e];
    }
}

// ---------- weight transpose+fp16: W[k][n] fp32 -> WT[n][k] fp16 (both W1,W2) ----------

__global__ __launch_bounds__(256) void convert_w_kernel(
    const float* __restrict__ W1, const float* __restrict__ W2,
    _Float16* __restrict__ T1, _Float16* __restrict__ T2) {
    __shared__ float tile[64][65];
    int id = blockIdx.x;
    const float* W;  _Float16* WT;
    if (id < 64) { W = W1; WT = T1; }
    else         { W = W2; WT = T2; id -= 64; }
    int k0 = (id & 7) * 64, n0 = (id >> 3) * 64;
    int tr = threadIdx.x >> 4;
    int tc4 = (threadIdx.x & 15) * 4;
#pragma unroll
    for (int i = 0; i < 4; ++i) {
        int r = tr + i * 16;
        float4 v = *(const float4*)(W + (size_t)(k0 + r) * NF + n0 + tc4);
        tile[r][tc4 + 0] = v.x; tile[r][tc4 + 1] = v.y;
        tile[r][tc4 + 2] = v.z; tile[r][tc4 + 3] = v.w;
    }
    __syncthreads();
#pragma unroll
    for (int i = 0; i < 4; ++i) {
        int n = tr + i * 16;
        half4v hv;
#pragma unroll
        for (int j = 0; j < 4; ++j) hv[j] = (_Float16)tile[tc4 + j][n];
        *(half4v*)(WT + (size_t)(n0 + n) * NF + k0 + tc4) = hv;
    }
}

// ---------- x fp32 -> fp16 [Mp][512], zero pad rows ----------

__global__ __launch_bounds__(256) void convert_x_kernel(
    const float* __restrict__ x, _Float16* __restrict__ x16, int Nreal, int Mp) {
    int idx = blockIdx.x * 256 + threadIdx.x;  // one half8 per thread
    int row = idx >> 6;                        // 64 half8 per row
    int c8 = (idx & 63) * 8;
    if (row >= Mp) return;
    half8 hv = {0, 0, 0, 0, 0, 0, 0, 0};
    if (row < Nreal) {
        float4 v0 = *(const float4*)(x + (size_t)row * NF + c8);
        float4 v1 = *(const float4*)(x + (size_t)row * NF + c8 + 4);
        hv[0] = (_Float16)v0.x; hv[1] = (_Float16)v0.y;
        hv[2] = (_Float16)v0.z; hv[3] = (_Float16)v0.w;
        hv[4] = (_Float16)v1.x; hv[5] = (_Float16)v1.y;
        hv[6] = (_Float16)v1.z; hv[7] = (_Float16)v1.w;
    }
    *(half8*)(x16 + (size_t)row * NF + c8) = hv;
}

// ---------- fp16 MFMA GEMM: Ch[m,:] = fp16(rsqrt(deg[m]) * (A[m,:] @ B)) ----------
// 64x128 tile, 4 waves (2x2, wave tile 32x64), BK=64, 628 blocks.
// LDS chunk-XOR swizzle done on the GLOBAL side (global_load_lds forces lane->LDS contiguity):
// physical chunk (lane&7) of row r holds global chunk (lane&7)^(r&7); frag reads apply same XOR.

__global__ __launch_bounds__(256) void gemm_mfma_kernel(
    const _Float16* __restrict__ A, const _Float16* __restrict__ BT,
    const int* __restrict__ counts, _Float16* __restrict__ Ch) {
    __shared__ _Float16 lds[GBM * 64 + GBN * 64];  // 24 KB: As[64][64] | Bs[128][64]
    _Float16* As = lds;
    _Float16* Bs = lds + GBM * 64;

    int t = threadIdx.x;
    int w = t >> 6, lane = t & 63, l15 = lane & 15, q = lane >> 4;
    int m0 = (blockIdx.x >> 2) * GBM;   // adjacent blocks share the A stripe
    int n0 = (blockIdx.x & 3) * GBN;
    int wr = w >> 1, wc = w & 1;        // 2x2 wave grid; wave tile 32x64

    // staging: lane -> row lane>>3, swizzled k-chunk ((lane&7)^(row&7))*8 halves (16B)
    int gr = lane >> 3;
    int gc = ((lane & 7) ^ (gr & 7)) * 8;
    const _Float16* Ag0 = A + (size_t)(m0 + w * 8 + gr) * NF + gc;
    const _Float16* Ag1 = A + (size_t)(m0 + 32 + w * 8 + gr) * NF + gc;
    const _Float16* Bg0 = BT + (size_t)(n0 + w * 8 + gr) * NF + gc;
    const _Float16* Bg1 = BT + (size_t)(n0 + 32 + w * 8 + gr) * NF + gc;
    const _Float16* Bg2 = BT + (size_t)(n0 + 64 + w * 8 + gr) * NF + gc;
    const _Float16* Bg3 = BT + (size_t)(n0 + 96 + w * 8 + gr) * NF + gc;
    // wave-uniform LDS destinations (8 rows per wave per instr)
    _Float16* As_d0 = As + (w * 8) * 64;
    _Float16* As_d1 = As + (32 + w * 8) * 64;
    _Float16* Bs_d0 = Bs + (w * 8) * 64;
    _Float16* Bs_d1 = Bs + (32 + w * 8) * 64;
    _Float16* Bs_d2 = Bs + (64 + w * 8) * 64;
    _Float16* Bs_d3 = Bs + (96 + w * 8) * 64;

    f32x4 acc[2][4] = {};

    for (int k0 = 0; k0 < NF; k0 += 64) {
        GLOAD_LDS16(Ag0 + k0, As_d0);
        GLOAD_LDS16(Ag1 + k0, As_d1);
        GLOAD_LDS16(Bg0 + k0, Bs_d0);
        GLOAD_LDS16(Bg1 + k0, Bs_d1);
        GLOAD_LDS16(Bg2 + k0, Bs_d2);
        GLOAD_LDS16(Bg3 + k0, Bs_d3);
        __syncthreads();

        int key = l15 & 7;
#pragma unroll
        for (int kk = 0; kk < 2; ++kk) {
            int ch = ((kk * 4 + q) ^ key) * 8;  // swizzled k-chunk for this lane
            half8 a[2], b[4];
#pragma unroll
            for (int r = 0; r < 2; ++r)
                a[r] = *(const half8*)(As + (wr * 32 + r * 16 + l15) * 64 + ch);
#pragma unroll
            for (int c = 0; c < 4; ++c)
                b[c] = *(const half8*)(Bs + (wc * 64 + c * 16 + l15) * 64 + ch);
#pragma unroll
            for (int r = 0; r < 2; ++r)
#pragma unroll
                for (int c = 0; c < 4; ++c)
                    acc[r][c] = __builtin_amdgcn_mfma_f32_16x16x32_f16(a[r], b[c], acc[r][c], 0, 0, 0);
        }
        __syncthreads();
    }

    // C/D layout: col = l15, row = q*4 + reg
#pragma unroll
    for (int r = 0; r < 2; ++r)
#pragma unroll
        for (int i = 0; i < 4; ++i) {
            int row = m0 + wr * 32 + r * 16 + q * 4 + i;
            float dv = rsqrtf((float)counts[row] + 1.0f);
#pragma unroll
            for (int c = 0; c < 4; ++c) {
                int col = n0 + wc * 64 + c * 16 + l15;
                Ch[(size_t)row * NF + col] = (_Float16)(acc[r][c][i] * dv);
            }
        }
}

// ---------- quarter-wave CSR aggregation over fp16 h-buffer ----------
// chunk = blockIdx.x & 3 (rides block->XCD round-robin; 2.5 MB slice per XCD-L2).
// lane = 16*g + j: quarter g takes 4 consecutive edges (int4 index load); lane loads
// half8 (16 B of features at chunk*128 + j*8); butterfly-reduce quarters; emit fp16.

__global__ __launch_bounds__(256) void agg_kernel(
    const _Float16* __restrict__ hb, const int* __restrict__ counts,
    const int* __restrict__ src_pad, const float* __restrict__ bias,
    _Float16* __restrict__ out_h, int Mreal) {
    int chunk = blockIdx.x & (NCHUNK - 1);
    int node = (blockIdx.x >> 2) * 4 + (threadIdx.x >> 6);
    int lane = threadIdx.x & 63;
    int g = lane >> 4;
    int j = lane & 15;
    int f8 = chunk * 128 + j * 8;
    size_t obase = (size_t)node * NF + f8;

    if (node >= Mreal) {  // pad rows must be zero when consumed as GEMM-A
        if (g == 0) {
            half8 z = {0, 0, 0, 0, 0, 0, 0, 0};
            *(half8*)(out_h + obase) = z;
        }
        return;
    }

    int cntr = counts[node];
    int cnt = cntr < PAD_DEG ? cntr : PAD_DEG;
    const int* sp = src_pad + (size_t)node * PAD_DEG;

    float acc[8] = {};
    for (int e = 0; e < cnt; e += 16) {
        int4 s4 = *(const int4*)(sp + e + g * 4);   // quarter g: edges e+4g .. e+4g+3
        int base = e + g * 4;
        int sidx[4] = {s4.x, s4.y, s4.z, s4.w};
#pragma unroll
        for (int tq = 0; tq < 4; ++tq) {
            bool ok = (base + tq) < cnt;
            int srow = ok ? sidx[tq] : node;        // safe hot fallback row
            float m = ok ? 1.f : 0.f;
            half8 hv = *(const half8*)(hb + (size_t)srow * NF + f8);
#pragma unroll
            for (int k = 0; k < 8; ++k) acc[k] = fmaf(m, (float)hv[k], acc[k]);
        }
    }

#pragma unroll
    for (int k = 0; k < 8; ++k) {
        acc[k] += __shfl_xor(acc[k], 16);
        acc[k] += __shfl_xor(acc[k], 32);
    }

    if (g != 0) return;

    half8 sv = *(const half8*)(hb + obase);  // self row
    float dv = rsqrtf((float)cntr + 1.0f);
    half8 o8;
#pragma unroll
    for (int k = 0; k < 8; ++k) {
        float o = fmaxf(fmaf(dv, acc[k] + (float)sv[k], bias[f8 + k]), 0.f);
        o8[k] = (_Float16)o;
    }
    *(half8*)(out_h + obase) = o8;
}

// ---------- head: out[n,o] = h2[n,:] @ Wl[:,o] + bl[o]  (fp16 in, fp32 out) ----------

__global__ __launch_bounds__(256) void head_kernel(
    const _Float16* __restrict__ in, const float* __restrict__ Wl,
    const float* __restrict__ bl, float* __restrict__ out, int M) {
    __shared__ float Ws[NF * OUT_F];  // 32 KB
    int tid = threadIdx.x;
    for (int i = tid; i < NF * OUT_F; i += 256) Ws[i] = Wl[i];
    __syncthreads();
    int node = blockIdx.x * 16 + (tid >> 4);
    int o = tid & 15;
    if (node >= M) return;
    const half8* row8 = (const half8*)(in + (size_t)node * NF);
    float acc = 0.f;
#pragma unroll 2
    for (int k8 = 0; k8 < NF / 8; ++k8) {
        half8 hv = row8[k8];
        int kb = k8 * 8;
#pragma unroll
        for (int u = 0; u < 8; ++u)
            acc = fmaf((float)hv[u], Ws[(kb + u) * OUT_F + o], acc);
    }
    out[(size_t)node * OUT_F + o] = acc + bl[o];
}

// ---------- launch ----------

extern "C" void kernel_launch(void* const* d_in, const int* in_sizes, int n_in,
                              void* d_out, int out_size, void* d_ws, size_t ws_size,
                              hipStream_t stream) {
    const float* x  = (const float*)d_in[0];
    const int* eidx = (const int*)d_in[1];
    const float* W1 = (const float*)d_in[2];
    const float* b1 = (const float*)d_in[3];
    const float* W2 = (const float*)d_in[4];
    const float* b2 = (const float*)d_in[5];
    const float* Wl = (const float*)d_in[6];
    const float* bl = (const float*)d_in[7];

    int N = in_sizes[0] / NF;
    int E = in_sizes[1] / 2;
    int Mp = (N + GBM - 1) & ~(GBM - 1);
    const int* src = eidx;
    const int* dst = eidx + E;

    char* p = (char*)d_ws;
    auto carve = [&](size_t bytes) -> void* {
        void* r = (void*)p;
        p += (bytes + 255) & ~(size_t)255;
        return r;
    };
    _Float16* hbuf = (_Float16*)carve((size_t)Mp * NF * sizeof(_Float16));  // GEMM outputs
    _Float16* abuf = (_Float16*)carve((size_t)Mp * NF * sizeof(_Float16));  // x16 / agg outs (GEMM A, head in)
    _Float16* W1T  = (_Float16*)carve((size_t)NF * NF * sizeof(_Float16));
    _Float16* W2T  = (_Float16*)carve((size_t)NF * NF * sizeof(_Float16));
    int* counts    = (int*)carve((size_t)Mp * sizeof(int));
    int* src_pad   = (int*)carve((size_t)N * PAD_DEG * sizeof(int));

    hipMemsetAsync(counts, 0, (size_t)Mp * sizeof(int), stream);

    edge_prep_kernel<<<dim3((E + 255) / 256), dim3(256), 0, stream>>>(src, dst, counts, src_pad, E);
    convert_w_kernel<<<dim3(128), dim3(256), 0, stream>>>(W1, W2, W1T, W2T);
    convert_x_kernel<<<dim3(Mp / 4), dim3(256), 0, stream>>>(x, abuf, N, Mp);

    dim3 gg((Mp / GBM) * (NF / GBN));   // 628 blocks
    dim3 ga(Mp);                        // (Mp/4 node groups) x 4 chunks

    // layer 1
    gemm_mfma_kernel<<<gg, dim3(256), 0, stream>>>(abuf, W1T, counts, hbuf);
    agg_kernel<<<ga, dim3(256), 0, stream>>>(hbuf, counts, src_pad, b1, abuf, N);
    // layer 2
    gemm_mfma_kernel<<<gg, dim3(256), 0, stream>>>(abuf, W2T, counts, hbuf);
    agg_kernel<<<ga, dim3(256), 0, stream>>>(hbuf, counts, src_pad, b2, abuf, N);
    // head
    head_kernel<<<dim3((N + 15) / 16), dim3(256), 0, stream>>>(abuf, Wl, bl, (float*)d_out, N);
}

// Round 8
// 169.148 us; speedup vs baseline: 1.5778x; 1.0203x over previous
//
#include <hip/hip_runtime.h>
#include <stdint.h>

#define NF 512
#define OUT_F 16
#define PAD_DEG 128
#define GBM 64
#define GBN 128

typedef __attribute__((ext_vector_type(8))) _Float16 half8;
typedef __attribute__((ext_vector_type(4))) _Float16 half4v;
typedef __attribute__((ext_vector_type(4))) float f32x4;

// async 16B/lane global->LDS: lds dst is wave-uniform base + lane*16
#define GLOAD_LDS16(g, l) \
  __builtin_amdgcn_global_load_lds((const __attribute__((address_space(1))) unsigned int*)(g), \
                                   (__attribute__((address_space(3))) unsigned int*)(l), 16, 0, 0)

// ---------- fused prep: [0,128) convert W1/W2 | [128,128+Mp/4) convert x | rest edge prep ----------

__global__ __launch_bounds__(256) void prep_kernel(
    const float* __restrict__ W1, const float* __restrict__ W2,
    _Float16* __restrict__ T1, _Float16* __restrict__ T2,
    const float* __restrict__ x, _Float16* __restrict__ x16,
    const int* __restrict__ src, const int* __restrict__ dst,
    int* __restrict__ counts, int* __restrict__ src_pad,
    int E, int Nreal, int Mp) {
    __shared__ float tile[64][65];
    int b = blockIdx.x;
    int xblocks = Mp / 4;

    if (b < 128) {
        // ---- weight transpose + fp16: W[k][n] -> WT[n][k] ----
        int id = b;
        const float* W;  _Float16* WT;
        if (id < 64) { W = W1; WT = T1; }
        else         { W = W2; WT = T2; id -= 64; }
        int k0 = (id & 7) * 64, n0 = (id >> 3) * 64;
        int tr = threadIdx.x >> 4;
        int tc4 = (threadIdx.x & 15) * 4;
#pragma unroll
        for (int i = 0; i < 4; ++i) {
            int r = tr + i * 16;
            float4 v = *(const float4*)(W + (size_t)(k0 + r) * NF + n0 + tc4);
            tile[r][tc4 + 0] = v.x; tile[r][tc4 + 1] = v.y;
            tile[r][tc4 + 2] = v.z; tile[r][tc4 + 3] = v.w;
        }
        __syncthreads();
#pragma unroll
        for (int i = 0; i < 4; ++i) {
            int n = tr + i * 16;
            half4v hv;
#pragma unroll
            for (int j = 0; j < 4; ++j) hv[j] = (_Float16)tile[tc4 + j][n];
            *(half4v*)(WT + (size_t)(n0 + n) * NF + k0 + tc4) = hv;
        }
    } else if (b < 128 + xblocks) {
        // ---- x fp32 -> fp16, zero pad rows ----
        int idx = (b - 128) * 256 + threadIdx.x;  // one half8 per thread
        int row = idx >> 6;
        int c8 = (idx & 63) * 8;
        if (row >= Mp) return;
        half8 hv = {0, 0, 0, 0, 0, 0, 0, 0};
        if (row < Nreal) {
            float4 v0 = *(const float4*)(x + (size_t)row * NF + c8);
            float4 v1 = *(const float4*)(x + (size_t)row * NF + c8 + 4);
            hv[0] = (_Float16)v0.x; hv[1] = (_Float16)v0.y;
            hv[2] = (_Float16)v0.z; hv[3] = (_Float16)v0.w;
            hv[4] = (_Float16)v1.x; hv[5] = (_Float16)v1.y;
            hv[6] = (_Float16)v1.z; hv[7] = (_Float16)v1.w;
        }
        *(half8*)(x16 + (size_t)row * NF + c8) = hv;
    } else {
        // ---- edge prep: in-degree count + padded adjacency ----
        int e = (b - 128 - xblocks) * 256 + threadIdx.x;
        if (e < E) {
            int d = dst[e];
            int slot = atomicAdd(&counts[d], 1);
            if (slot < PAD_DEG) src_pad[(size_t)d * PAD_DEG + slot] = src[e];
        }
    }
}

// ---------- fp16 MFMA GEMM: Ch[m,:] = fp16(rsqrt(deg[m]) * (A[m,:] @ B)) ----------
// 64x128 tile, 4 waves (2x2, wave tile 32x64), BK=64.
// LDS chunk-XOR swizzle applied on the GLOBAL side (global_load_lds forces lane->LDS contiguity).

__global__ __launch_bounds__(256) void gemm_mfma_kernel(
    const _Float16* __restrict__ A, const _Float16* __restrict__ BT,
    const int* __restrict__ counts, _Float16* __restrict__ Ch) {
    __shared__ _Float16 lds[GBM * 64 + GBN * 64];  // 24 KB: As[64][64] | Bs[128][64]
    _Float16* As = lds;
    _Float16* Bs = lds + GBM * 64;

    int t = threadIdx.x;
    int w = t >> 6, lane = t & 63, l15 = lane & 15, q = lane >> 4;
    int m0 = (blockIdx.x >> 2) * GBM;   // adjacent blocks share the A stripe
    int n0 = (blockIdx.x & 3) * GBN;
    int wr = w >> 1, wc = w & 1;        // 2x2 wave grid; wave tile 32x64

    int gr = lane >> 3;
    int gc = ((lane & 7) ^ (gr & 7)) * 8;
    const _Float16* Ag0 = A + (size_t)(m0 + w * 8 + gr) * NF + gc;
    const _Float16* Ag1 = A + (size_t)(m0 + 32 + w * 8 + gr) * NF + gc;
    const _Float16* Bg0 = BT + (size_t)(n0 + w * 8 + gr) * NF + gc;
    const _Float16* Bg1 = BT + (size_t)(n0 + 32 + w * 8 + gr) * NF + gc;
    const _Float16* Bg2 = BT + (size_t)(n0 + 64 + w * 8 + gr) * NF + gc;
    const _Float16* Bg3 = BT + (size_t)(n0 + 96 + w * 8 + gr) * NF + gc;
    _Float16* As_d0 = As + (w * 8) * 64;
    _Float16* As_d1 = As + (32 + w * 8) * 64;
    _Float16* Bs_d0 = Bs + (w * 8) * 64;
    _Float16* Bs_d1 = Bs + (32 + w * 8) * 64;
    _Float16* Bs_d2 = Bs + (64 + w * 8) * 64;
    _Float16* Bs_d3 = Bs + (96 + w * 8) * 64;

    f32x4 acc[2][4] = {};

    for (int k0 = 0; k0 < NF; k0 += 64) {
        GLOAD_LDS16(Ag0 + k0, As_d0);
        GLOAD_LDS16(Ag1 + k0, As_d1);
        GLOAD_LDS16(Bg0 + k0, Bs_d0);
        GLOAD_LDS16(Bg1 + k0, Bs_d1);
        GLOAD_LDS16(Bg2 + k0, Bs_d2);
        GLOAD_LDS16(Bg3 + k0, Bs_d3);
        __syncthreads();

        int key = l15 & 7;
#pragma unroll
        for (int kk = 0; kk < 2; ++kk) {
            int ch = ((kk * 4 + q) ^ key) * 8;  // swizzled k-chunk for this lane
            half8 a[2], b[4];
#pragma unroll
            for (int r = 0; r < 2; ++r)
                a[r] = *(const half8*)(As + (wr * 32 + r * 16 + l15) * 64 + ch);
#pragma unroll
            for (int c = 0; c < 4; ++c)
                b[c] = *(const half8*)(Bs + (wc * 64 + c * 16 + l15) * 64 + ch);
#pragma unroll
            for (int r = 0; r < 2; ++r)
#pragma unroll
                for (int c = 0; c < 4; ++c)
                    acc[r][c] = __builtin_amdgcn_mfma_f32_16x16x32_f16(a[r], b[c], acc[r][c], 0, 0, 0);
        }
        __syncthreads();
    }

    // C/D layout: col = l15, row = q*4 + reg
#pragma unroll
    for (int r = 0; r < 2; ++r)
#pragma unroll
        for (int i = 0; i < 4; ++i) {
            int row = m0 + wr * 32 + r * 16 + q * 4 + i;
            float dv = rsqrtf((float)counts[row] + 1.0f);
#pragma unroll
            for (int c = 0; c < 4; ++c) {
                int col = n0 + wc * 64 + c * 16 + l15;
                Ch[(size_t)row * NF + col] = (_Float16)(acc[r][c][i] * dv);
            }
        }
}

// ---------- one-wave-per-node CSR aggregation over fp16 h-buffer ----------
// Wave-uniform node -> counts/src_pad reads become SCALAR loads; each edge gather is ONE
// 1 KB vector load (64 lanes x half8). No cross-lane reduction, no masks.

__global__ __launch_bounds__(256) void agg_kernel(
    const _Float16* __restrict__ hb, const int* __restrict__ counts,
    const int* __restrict__ src_pad, const float* __restrict__ bias,
    _Float16* __restrict__ out_h, int Mreal) {
    int node = __builtin_amdgcn_readfirstlane(blockIdx.x * 4 + (threadIdx.x >> 6));
    int lane = threadIdx.x & 63;
    int f8 = lane * 8;
    size_t obase = (size_t)node * NF + f8;

    if (node >= Mreal) {  // pad rows must be zero when consumed as GEMM-A
        half8 z = {0, 0, 0, 0, 0, 0, 0, 0};
        *(half8*)(out_h + obase) = z;
        return;
    }

    int cntr = counts[node];
    int cnt = cntr < PAD_DEG ? cntr : PAD_DEG;
    const int* sp = src_pad + (size_t)node * PAD_DEG;

    half8 sv = *(const half8*)(hb + obase);  // self row (overlaps with gather)
    float4 b0 = *(const float4*)(bias + f8);
    float4 b1 = *(const float4*)(bias + f8 + 4);

    float acc[8] = {};
    int e = 0;
    for (; e + 3 < cnt; e += 4) {
        int s0 = sp[e], s1 = sp[e + 1], s2 = sp[e + 2], s3 = sp[e + 3];
        half8 v0 = *(const half8*)(hb + (size_t)s0 * NF + f8);
        half8 v1 = *(const half8*)(hb + (size_t)s1 * NF + f8);
        half8 v2 = *(const half8*)(hb + (size_t)s2 * NF + f8);
        half8 v3 = *(const half8*)(hb + (size_t)s3 * NF + f8);
#pragma unroll
        for (int k = 0; k < 8; ++k)
            acc[k] += ((float)v0[k] + (float)v1[k]) + ((float)v2[k] + (float)v3[k]);
    }
    for (; e < cnt; ++e) {
        int s = sp[e];
        half8 v = *(const half8*)(hb + (size_t)s * NF + f8);
#pragma unroll
        for (int k = 0; k < 8; ++k) acc[k] += (float)v[k];
    }

    float dv = rsqrtf((float)cntr + 1.0f);
    float bb[8] = {b0.x, b0.y, b0.z, b0.w, b1.x, b1.y, b1.z, b1.w};
    half8 o8;
#pragma unroll
    for (int k = 0; k < 8; ++k) {
        float o = fmaxf(fmaf(dv, acc[k] + (float)sv[k], bb[k]), 0.f);
        o8[k] = (_Float16)o;
    }
    *(half8*)(out_h + obase) = o8;
}

// ---------- head: out[n,o] = h2[n,:] @ Wl[:,o] + bl[o]  (fp16 in, fp32 out) ----------

__global__ __launch_bounds__(256) void head_kernel(
    const _Float16* __restrict__ in, const float* __restrict__ Wl,
    const float* __restrict__ bl, float* __restrict__ out, int M) {
    __shared__ float Ws[NF * OUT_F];  // 32 KB
    int tid = threadIdx.x;
    for (int i = tid; i < NF * OUT_F; i += 256) Ws[i] = Wl[i];
    __syncthreads();
    int node = blockIdx.x * 16 + (tid >> 4);
    int o = tid & 15;
    if (node >= M) return;
    const half8* row8 = (const half8*)(in + (size_t)node * NF);
    float acc = 0.f;
#pragma unroll 2
    for (int k8 = 0; k8 < NF / 8; ++k8) {
        half8 hv = row8[k8];
        int kb = k8 * 8;
#pragma unroll
        for (int u = 0; u < 8; ++u)
            acc = fmaf((float)hv[u], Ws[(kb + u) * OUT_F + o], acc);
    }
    out[(size_t)node * OUT_F + o] = acc + bl[o];
}

// ---------- launch ----------

extern "C" void kernel_launch(void* const* d_in, const int* in_sizes, int n_in,
                              void* d_out, int out_size, void* d_ws, size_t ws_size,
                              hipStream_t stream) {
    const float* x  = (const float*)d_in[0];
    const int* eidx = (const int*)d_in[1];
    const float* W1 = (const float*)d_in[2];
    const float* b1 = (const float*)d_in[3];
    const float* W2 = (const float*)d_in[4];
    const float* b2 = (const float*)d_in[5];
    const float* Wl = (const float*)d_in[6];
    const float* bl = (const float*)d_in[7];

    int N = in_sizes[0] / NF;
    int E = in_sizes[1] / 2;
    int Mp = (N + GBM - 1) & ~(GBM - 1);
    const int* src = eidx;
    const int* dst = eidx + E;

    char* p = (char*)d_ws;
    auto carve = [&](size_t bytes) -> void* {
        void* r = (void*)p;
        p += (bytes + 255) & ~(size_t)255;
        return r;
    };
    _Float16* hbuf = (_Float16*)carve((size_t)Mp * NF * sizeof(_Float16));  // GEMM outputs
    _Float16* abuf = (_Float16*)carve((size_t)Mp * NF * sizeof(_Float16));  // x16 / agg outs
    _Float16* W1T  = (_Float16*)carve((size_t)NF * NF * sizeof(_Float16));
    _Float16* W2T  = (_Float16*)carve((size_t)NF * NF * sizeof(_Float16));
    int* counts    = (int*)carve((size_t)Mp * sizeof(int));
    int* src_pad   = (int*)carve((size_t)N * PAD_DEG * sizeof(int));

    hipMemsetAsync(counts, 0, (size_t)Mp * sizeof(int), stream);

    int xblocks = Mp / 4;
    int eblocks = (E + 255) / 256;
    prep_kernel<<<dim3(128 + xblocks + eblocks), dim3(256), 0, stream>>>(
        W1, W2, W1T, W2T, x, abuf, src, dst, counts, src_pad, E, N, Mp);

    dim3 gg((Mp / GBM) * (NF / GBN));   // 628 blocks
    dim3 ga(Mp / 4);                    // one wave per node

    // layer 1
    gemm_mfma_kernel<<<gg, dim3(256), 0, stream>>>(abuf, W1T, counts, hbuf);
    agg_kernel<<<ga, dim3(256), 0, stream>>>(hbuf, counts, src_pad, b1, abuf, N);
    // layer 2
    gemm_mfma_kernel<<<gg, dim3(256), 0, stream>>>(abuf, W2T, counts, hbuf);
    agg_kernel<<<ga, dim3(256), 0, stream>>>(hbuf, counts, src_pad, b2, abuf, N);
    // head
    head_kernel<<<dim3((N + 15) / 16), dim3(256), 0, stream>>>(abuf, Wl, bl, (float*)d_out, N);
}